// Round 1
// baseline (9596.782 us; speedup 1.0000x reference)
//
#include <hip/hip_runtime.h>

// ---------------------------------------------------------------------------
// BiGRU encoder, MI355X. Persistent cooperative-style recurrence.
// B=16, T=2048, N=1025, F=512, L=10. Output (16, 2028, 1024) fp32.
//
// ws layout:
//   Xb    [T][B][F] bf16   33,554,432 B   (x cast to bf16, time-major)
//   Hf    [T][B][F] bf16   33,554,432 B   (forward hidden states, bf16)
//   Hb    [T][B][F] bf16   33,554,432 B   (backward hidden states)
//   Wb    [2][2][1536][512] bf16  6,291,456 B  (dir, src{0=Whh,1=Wih})
//   flags 2*32 slots * 128B      8,192 B  (per-block progress counters)
// total ~102 MB.
// ---------------------------------------------------------------------------

#define TT    2048
#define BB    16
#define FF    512
#define LL    10
#define NBLK  32          // blocks per direction
#define NTHR  384         // 6 waves

typedef __attribute__((ext_vector_type(8))) short short8;
typedef __attribute__((ext_vector_type(4))) float f32x4;

__device__ __forceinline__ unsigned short f2bf(float f) {
  union { float f; unsigned int u; } v; v.f = f;
  unsigned int u = v.u;
  unsigned int r = (u + 0x7fffu + ((u >> 16) & 1u)) >> 16;
  return (unsigned short)r;
}
__device__ __forceinline__ float bf2f(unsigned short h) {
  union { unsigned int u; float f; } v; v.u = ((unsigned int)h) << 16;
  return v.f;
}

// --- prep: cast x (B,T,N) f32 -> Xb (T,B,F) bf16 ---------------------------
__global__ void prep_x(const float* __restrict__ x, unsigned short* __restrict__ Xb) {
  int i = blockIdx.x * blockDim.x + threadIdx.x;     // over T*B*F = 16,777,216
  int f = i & (FF - 1);
  int b = (i >> 9) & (BB - 1);
  int t = i >> 13;
  Xb[i] = f2bf(x[(size_t)b * (TT * 1025) + t * 1025 + f]);
}

// --- prep: cast weights to bf16, order [Whh_f, Wih_f, Whh_b, Wih_b] --------
__global__ void prep_w(const float* __restrict__ a, const float* __restrict__ b,
                       const float* __restrict__ c, const float* __restrict__ d,
                       unsigned short* __restrict__ Wb) {
  const int M = 1536 * 512;
  int i = blockIdx.x * blockDim.x + threadIdx.x;     // over 4*M = 3,145,728
  int m = i / M, r = i - m * M;
  const float* src = (m == 0) ? a : (m == 1) ? b : (m == 2) ? c : d;
  Wb[i] = f2bf(src[r]);
}

__global__ void prep_flags(int* __restrict__ flags) {
  int i = blockIdx.x * blockDim.x + threadIdx.x;
  if (i < 2 * NBLK * 32) flags[i] = 0;
}

// --- persistent recurrent kernel -------------------------------------------
// 64 blocks: blockIdx>>5 = direction, blockIdx&31 = hidden-column slice (16 cols).
// waves 0..2: gh = h@Whh^T (gates r,z,n)  -- critical path
// waves 3..5: gi = x@Wih^T (gates r,z,n)  -- overlaps the inter-block wait
__global__ void __launch_bounds__(NTHR, 1) bigru_rec(
    const unsigned short* __restrict__ Xb,
    unsigned short* __restrict__ Hf, unsigned short* __restrict__ Hb,
    const unsigned short* __restrict__ Wb,
    const float* __restrict__ bih_f, const float* __restrict__ bhh_f,
    const float* __restrict__ bih_b, const float* __restrict__ bhh_b,
    int* __restrict__ flags, float* __restrict__ out)
{
  const int bid  = blockIdx.x;
  const int d    = bid >> 5;
  const int j    = bid & 31;
  const int tid  = threadIdx.x;
  const int w    = tid >> 6;
  const int lane = tid & 63;

  unsigned short* Hst = d ? Hb : Hf;
  int* flg  = flags + d * NBLK * 32;       // 32 slots, 128B apart
  const float* bih = d ? bih_b : bih_f;
  const float* bhh = d ? bhh_b : bhh_f;

  __shared__ float acc_lds[6][16][17];

  const int g   = (w >= 3) ? (w - 3) : w;  // gate 0=r 1=z 2=n
  const int src = (w >= 3) ? 1 : 0;        // 0=Whh (gh), 1=Wih (gi)
  const int l15 = lane & 15;
  const int lk  = (lane >> 4) * 8;

  // weight fragments for this wave's N-tile: rows g*512 + j*16 + (lane&15)
  short8 wfrag[16];
  {
    const unsigned short* wrow =
        Wb + (size_t)((d * 2 + src) * 1536 + g * 512 + j * 16 + l15) * 512 + lk;
#pragma unroll
    for (int kk = 0; kk < 16; ++kk)
      wfrag[kk] = *(const short8*)(wrow + kk * 32);
  }

  // elementwise thread mapping (threads 0..255): m = batch row, f = col in slice
  const int m = tid >> 4, f = tid & 15;
  const int col = j * 16 + f;
  float br_i = 0.f, br_h = 0.f, bz_i = 0.f, bz_h = 0.f, bn_i = 0.f, bn_h = 0.f;
  float hcarry = 0.f;                      // fp32 recurrent carry (exact)
  if (tid < 256) {
    br_i = bih[col];        br_h = bhh[col];
    bz_i = bih[512 + col];  bz_h = bhh[512 + col];
    bn_i = bih[1024 + col]; bn_h = bhh[1024 + col];
  }
  const int* slot = flg + (lane & 31) * 32;
  __syncthreads();

  for (int t = 0; t < TT; ++t) {
    const int tx = d ? (TT - 1 - t) : t;

    // early-issue residual x load (used in phase 2)
    float xv = 0.f;
    if (tid < 256) xv = bf2f(Xb[(size_t)(tx * BB + m) * FF + col]);

    f32x4 acc0 = {0.f, 0.f, 0.f, 0.f}, acc1 = {0.f, 0.f, 0.f, 0.f};
    const unsigned short* Arow = nullptr;
    if (src == 1) {
      Arow = Xb + (size_t)(tx * BB + l15) * FF + lk;
    } else if (t > 0) {
      // wait until every block has published h_{t-1}: slot value >= t
      int vv;
      do {
        vv = __hip_atomic_load(slot, __ATOMIC_RELAXED, __HIP_MEMORY_SCOPE_AGENT);
      } while (!__all(vv >= t));
      __builtin_amdgcn_fence(__ATOMIC_ACQUIRE, "workgroup");  // no hoisting of h loads
      Arow = Hst + (size_t)((t - 1) * BB + l15) * FF + lk;
    }

    if (Arow) {
      short8 af[16];
#pragma unroll
      for (int kk = 0; kk < 16; ++kk)
        af[kk] = *(const short8*)(Arow + kk * 32);
#pragma unroll
      for (int kk = 0; kk < 16; kk += 2) {
        acc0 = __builtin_amdgcn_mfma_f32_16x16x32_bf16(af[kk],     wfrag[kk],     acc0, 0, 0, 0);
        acc1 = __builtin_amdgcn_mfma_f32_16x16x32_bf16(af[kk + 1], wfrag[kk + 1], acc1, 0, 0, 0);
      }
    }
    // D layout (verified m89): col = lane&15, row = (lane>>4)*4 + reg
#pragma unroll
    for (int jj = 0; jj < 4; ++jj)
      acc_lds[w][(lane >> 4) * 4 + jj][l15] = acc0[jj] + acc1[jj];
    __syncthreads();

    if (tid < 256) {
      const float ghr = acc_lds[0][m][f] + br_h;
      const float ghz = acc_lds[1][m][f] + bz_h;
      const float ghn = acc_lds[2][m][f] + bn_h;
      const float gir = acc_lds[3][m][f] + br_i;
      const float giz = acc_lds[4][m][f] + bz_i;
      const float gin = acc_lds[5][m][f] + bn_i;
      const float r = 1.f / (1.f + __expf(-(gir + ghr)));
      const float z = 1.f / (1.f + __expf(-(giz + ghz)));
      const float e = __expf(2.f * (gin + r * ghn));
      const float n = 1.f - 2.f / (e + 1.f);          // tanh, inf-safe
      const float h2 = (1.f - z) * n + z * hcarry + xv;
      hcarry = h2;
      Hst[(size_t)(t * BB + m) * FF + col] = f2bf(h2);
      if (t >= LL && t < TT - LL)
        out[((size_t)m * (TT - 2 * LL) + (t - LL)) * 1024 + d * 512 + col] = h2;
    }
    __syncthreads();                       // all stores drained (barrier implies vmcnt(0))
    if (tid == 0)                          // publish: this block finished step t
      __hip_atomic_store(flg + j * 32, t + 1, __ATOMIC_RELEASE, __HIP_MEMORY_SCOPE_AGENT);
  }
}

// ---------------------------------------------------------------------------
extern "C" void kernel_launch(void* const* d_in, const int* in_sizes, int n_in,
                              void* d_out, int out_size, void* d_ws, size_t ws_size,
                              hipStream_t stream) {
  const float* x     = (const float*)d_in[0];
  const float* Wih_f = (const float*)d_in[1];
  const float* Whh_f = (const float*)d_in[2];
  const float* bih_f = (const float*)d_in[3];
  const float* bhh_f = (const float*)d_in[4];
  const float* Wih_b = (const float*)d_in[5];
  const float* Whh_b = (const float*)d_in[6];
  const float* bih_b = (const float*)d_in[7];
  const float* bhh_b = (const float*)d_in[8];
  float* out = (float*)d_out;

  char* ws = (char*)d_ws;
  unsigned short* Xb = (unsigned short*)ws;
  unsigned short* Hf = (unsigned short*)(ws + (size_t)33554432);
  unsigned short* Hb = (unsigned short*)(ws + (size_t)2 * 33554432);
  unsigned short* Wb = (unsigned short*)(ws + (size_t)3 * 33554432);
  int* flags         = (int*)(ws + (size_t)3 * 33554432 + 6291456);

  prep_x<<<65536, 256, 0, stream>>>(x, Xb);
  prep_w<<<12288, 256, 0, stream>>>(Whh_f, Wih_f, Whh_b, Wih_b, Wb);
  prep_flags<<<8, 256, 0, stream>>>(flags);
  bigru_rec<<<64, NTHR, 0, stream>>>(Xb, Hf, Hb, Wb, bih_f, bhh_f, bih_b, bhh_b,
                                     flags, out);
}

// Round 2
// 7508.439 us; speedup vs baseline: 1.2781x; 1.2781x over previous
//
#include <hip/hip_runtime.h>

// ---------------------------------------------------------------------------
// BiGRU encoder, MI355X. Persistent cooperative-style recurrence.
// B=16, T=2048, N=1025, F=512, L=10. Output (16, 2028, 1024) fp32.
//
// Round 2: kill the per-step buffer_wbl2 (agent-release) — publish h via
// write-through (sc1) relaxed atomic stores + relaxed flag; readers use plain
// loads (write-once-then-read addresses are cold in all reader caches).
//
// ws layout:
//   Xb    [T][B][F] bf16   33,554,432 B   (x cast to bf16, time-major)
//   Hf    [T][B][F] bf16   33,554,432 B   (forward hidden states, bf16)
//   Hb    [T][B][F] bf16   33,554,432 B   (backward hidden states)
//   Wb    [2][2][1536][512] bf16  6,291,456 B  (dir, src{0=Whh,1=Wih})
//   flags 2*32 int (contiguous, 1 line per direction)
// ---------------------------------------------------------------------------

#define TT    2048
#define BB    16
#define FF    512
#define LL    10
#define NBLK  32          // blocks per direction
#define NTHR  384         // 6 waves

typedef __attribute__((ext_vector_type(8))) short short8;
typedef __attribute__((ext_vector_type(4))) float f32x4;

__device__ __forceinline__ unsigned short f2bf(float f) {
  union { float f; unsigned int u; } v; v.f = f;
  unsigned int u = v.u;
  unsigned int r = (u + 0x7fffu + ((u >> 16) & 1u)) >> 16;
  return (unsigned short)r;
}
__device__ __forceinline__ float bf2f(unsigned short h) {
  union { unsigned int u; float f; } v; v.u = ((unsigned int)h) << 16;
  return v.f;
}

// --- prep: cast x (B,T,N) f32 -> Xb (T,B,F) bf16 ---------------------------
__global__ void prep_x(const float* __restrict__ x, unsigned short* __restrict__ Xb) {
  int i = blockIdx.x * blockDim.x + threadIdx.x;     // over T*B*F = 16,777,216
  int f = i & (FF - 1);
  int b = (i >> 9) & (BB - 1);
  int t = i >> 13;
  Xb[i] = f2bf(x[(size_t)b * (TT * 1025) + t * 1025 + f]);
}

// --- prep: cast weights to bf16, order [Whh_f, Wih_f, Whh_b, Wih_b] --------
__global__ void prep_w(const float* __restrict__ a, const float* __restrict__ b,
                       const float* __restrict__ c, const float* __restrict__ d,
                       unsigned short* __restrict__ Wb) {
  const int M = 1536 * 512;
  int i = blockIdx.x * blockDim.x + threadIdx.x;     // over 4*M = 3,145,728
  int m = i / M, r = i - m * M;
  const float* src = (m == 0) ? a : (m == 1) ? b : (m == 2) ? c : d;
  Wb[i] = f2bf(src[r]);
}

__global__ void prep_flags(int* __restrict__ flags) {
  int i = threadIdx.x;
  if (i < 2 * NBLK) flags[i] = 0;
}

// --- persistent recurrent kernel -------------------------------------------
// 64 blocks: blockIdx>>5 = direction, blockIdx&31 = hidden-column slice (16 cols).
// waves 0..2: gh = h@Whh^T (gates r,z,n)  -- critical path (wave 0 polls)
// waves 3..5: gi = x@Wih^T (gates r,z,n)  -- overlaps the inter-block wait
__global__ void __launch_bounds__(NTHR, 1) bigru_rec(
    const unsigned short* __restrict__ Xb,
    unsigned short* __restrict__ Hf, unsigned short* __restrict__ Hb,
    const unsigned short* __restrict__ Wb,
    const float* __restrict__ bih_f, const float* __restrict__ bhh_f,
    const float* __restrict__ bih_b, const float* __restrict__ bhh_b,
    int* __restrict__ flags, float* __restrict__ out)
{
  const int bid  = blockIdx.x;
  const int d    = bid >> 5;
  const int j    = bid & 31;
  const int tid  = threadIdx.x;
  const int w    = tid >> 6;
  const int lane = tid & 63;

  unsigned short* Hst = d ? Hb : Hf;
  int* flg  = flags + d * NBLK;            // 32 contiguous ints (1 line)
  const float* bih = d ? bih_b : bih_f;
  const float* bhh = d ? bhh_b : bhh_f;

  __shared__ float acc_lds[6][16][17];
  __shared__ int tok;

  const int g   = (w >= 3) ? (w - 3) : w;  // gate 0=r 1=z 2=n
  const int src = (w >= 3) ? 1 : 0;        // 0=Whh (gh), 1=Wih (gi)
  const int l15 = lane & 15;
  const int lk  = (lane >> 4) * 8;

  // weight fragments for this wave's N-tile: rows g*512 + j*16 + (lane&15)
  short8 wfrag[16];
  {
    const unsigned short* wrow =
        Wb + (size_t)((d * 2 + src) * 1536 + g * 512 + j * 16 + l15) * 512 + lk;
#pragma unroll
    for (int kk = 0; kk < 16; ++kk)
      wfrag[kk] = *(const short8*)(wrow + kk * 32);
  }

  // elementwise thread mapping (threads 0..255): m = batch row, f = col in slice
  const int m = tid >> 4, f = tid & 15;
  const int col = j * 16 + f;
  float br_i = 0.f, br_h = 0.f, bz_i = 0.f, bz_h = 0.f, bn_i = 0.f, bn_h = 0.f;
  float hcarry = 0.f;                      // fp32 recurrent carry (exact)
  if (tid < 256) {
    br_i = bih[col];        br_h = bhh[col];
    bz_i = bih[512 + col];  bz_h = bhh[512 + col];
    bn_i = bih[1024 + col]; bn_h = bhh[1024 + col];
  }
  if (tid == 0) tok = 0;
  __syncthreads();

  for (int t = 0; t < TT; ++t) {
    const int tx = d ? (TT - 1 - t) : t;

    // early-issue residual x load (used in phase 2)
    float xv = 0.f;
    if (tid < 256) xv = bf2f(Xb[(size_t)(tx * BB + m) * FF + col]);

    f32x4 acc0 = {0.f, 0.f, 0.f, 0.f}, acc1 = {0.f, 0.f, 0.f, 0.f};
    const unsigned short* Arow = nullptr;
    if (src == 1) {
      Arow = Xb + (size_t)(tx * BB + l15) * FF + lk;
    } else if (t > 0) {
      // wait until every block has published h_{t-1}: slot value >= t
      if (w == 0) {
        int vv = t;
        do {
          if (lane < NBLK)
            vv = __hip_atomic_load(flg + lane, __ATOMIC_RELAXED,
                                   __HIP_MEMORY_SCOPE_AGENT);
        } while (!__all(lane < NBLK ? (vv >= t) : true));
        __builtin_amdgcn_sched_barrier(0);   // no compiler hoisting past poll
        if (lane == 0)
          __hip_atomic_store(&tok, t, __ATOMIC_RELEASE,
                             __HIP_MEMORY_SCOPE_WORKGROUP);
      } else {
        while (__hip_atomic_load(&tok, __ATOMIC_ACQUIRE,
                                 __HIP_MEMORY_SCOPE_WORKGROUP) < t) {}
      }
      __builtin_amdgcn_sched_barrier(0);
      Arow = Hst + (size_t)((t - 1) * BB + l15) * FF + lk;   // plain loads: cold addrs
    }

    if (Arow) {
      short8 af[16];
#pragma unroll
      for (int kk = 0; kk < 16; ++kk)
        af[kk] = *(const short8*)(Arow + kk * 32);
#pragma unroll
      for (int kk = 0; kk < 16; kk += 2) {
        acc0 = __builtin_amdgcn_mfma_f32_16x16x32_bf16(af[kk],     wfrag[kk],     acc0, 0, 0, 0);
        acc1 = __builtin_amdgcn_mfma_f32_16x16x32_bf16(af[kk + 1], wfrag[kk + 1], acc1, 0, 0, 0);
      }
    }
    // D layout (verified m89): col = lane&15, row = (lane>>4)*4 + reg
#pragma unroll
    for (int jj = 0; jj < 4; ++jj)
      acc_lds[w][(lane >> 4) * 4 + jj][l15] = acc0[jj] + acc1[jj];
    __syncthreads();

    float h2 = 0.f;
    if (tid < 256) {
      const float ghr = acc_lds[0][m][f] + br_h;
      const float ghz = acc_lds[1][m][f] + bz_h;
      const float ghn = acc_lds[2][m][f] + bn_h;
      const float gir = acc_lds[3][m][f] + br_i;
      const float giz = acc_lds[4][m][f] + bz_i;
      const float gin = acc_lds[5][m][f] + bn_i;
      const float r = 1.f / (1.f + __expf(-(gir + ghr)));
      const float z = 1.f / (1.f + __expf(-(giz + ghz)));
      const float e = __expf(2.f * (gin + r * ghn));
      const float n = 1.f - 2.f / (e + 1.f);          // tanh, inf-safe
      h2 = (1.f - z) * n + z * hcarry + xv;
      hcarry = h2;
      // publish h as write-through (sc1) 4-byte relaxed atomics: pair lanes
      const unsigned short us = f2bf(h2);
      const unsigned int other =
          (unsigned int)(unsigned short)__shfl_xor((int)us, 1);
      if ((f & 1) == 0) {
        const unsigned int word = (unsigned int)us | (other << 16);
        unsigned int* wp = (unsigned int*)(Hst + (size_t)(t * BB + m) * FF + col);
        __hip_atomic_store(wp, word, __ATOMIC_RELAXED, __HIP_MEMORY_SCOPE_AGENT);
      }
    }
    __syncthreads();                       // implies vmcnt(0): h stores at coherence pt
    if (tid == 0)                          // publish: this block finished step t
      __hip_atomic_store(flg + j, t + 1, __ATOMIC_RELAXED, __HIP_MEMORY_SCOPE_AGENT);
    // out store AFTER publish: off the critical path
    if (tid < 256 && t >= LL && t < TT - LL)
      out[((size_t)m * (TT - 2 * LL) + (t - LL)) * 1024 + d * 512 + col] = h2;
  }
}

// ---------------------------------------------------------------------------
extern "C" void kernel_launch(void* const* d_in, const int* in_sizes, int n_in,
                              void* d_out, int out_size, void* d_ws, size_t ws_size,
                              hipStream_t stream) {
  const float* x     = (const float*)d_in[0];
  const float* Wih_f = (const float*)d_in[1];
  const float* Whh_f = (const float*)d_in[2];
  const float* bih_f = (const float*)d_in[3];
  const float* bhh_f = (const float*)d_in[4];
  const float* Wih_b = (const float*)d_in[5];
  const float* Whh_b = (const float*)d_in[6];
  const float* bih_b = (const float*)d_in[7];
  const float* bhh_b = (const float*)d_in[8];
  float* out = (float*)d_out;

  char* ws = (char*)d_ws;
  unsigned short* Xb = (unsigned short*)ws;
  unsigned short* Hf = (unsigned short*)(ws + (size_t)33554432);
  unsigned short* Hb = (unsigned short*)(ws + (size_t)2 * 33554432);
  unsigned short* Wb = (unsigned short*)(ws + (size_t)3 * 33554432);
  int* flags         = (int*)(ws + (size_t)3 * 33554432 + 6291456);

  prep_x<<<65536, 256, 0, stream>>>(x, Xb);
  prep_w<<<12288, 256, 0, stream>>>(Whh_f, Wih_f, Whh_b, Wih_b, Wb);
  prep_flags<<<1, 64, 0, stream>>>(flags);
  bigru_rec<<<64, NTHR, 0, stream>>>(Xb, Hf, Hb, Wb, bih_f, bhh_f, bih_b, bhh_b,
                                     flags, out);
}